// Round 11
// baseline (149.673 us; speedup 1.0000x reference)
//
#include <hip/hip_runtime.h>

// GNN EdgeConv, 3 layers, fp32 in/out.
// msg_e = relu(u[src]+w[dst]);  u = x@Wa^T (bf16), w = x@(Wb-Wa)^T + b (fp32).
// Round-14: dispatches 5 -> 4. k_prep deleted:
//  - gemm0 B is W0-direct fp32->bf16 in regs (proven correct r5-8; round-8's
//    regression re-attributed to holding fb across k_eg's gather -> occupancy
//    halved. Here fb lives only inside k_g0.)
//  - Wp layers 1,2 prepped inside k_g0 (gtid spans exactly 2x131072; consumers
//    are later dispatches)
//  - scatter is cursor-FREE: block b scans all dst (int4, L2-resident 256KB),
//    claims edges for its own 16 nodes via LDS atomics, writes own srcS
//    buckets + degG. No global cursor, no zeroing, no global atomics.
// k_eg / k_e2 untouched (deg source renamed). 4 dispatches:
// k_g0, k_eg(0), k_eg(1), k_e2.

#define NODES 4096
#define EDGES 65536
#define OSTR 1024   // out row stride (fp32)
#define DEGCAP 64   // max bucket size; deg ~ Poisson(16), P(>64) ~ 1e-18

typedef __attribute__((ext_vector_type(8))) short bf16x8;
typedef __attribute__((ext_vector_type(4))) float f32x4;

__device__ __forceinline__ unsigned short f2bf(float f) {
    unsigned int x = __float_as_uint(f);
    return (unsigned short)((x + 0x7fff + ((x >> 16) & 1)) >> 16); // RNE
}
__device__ __forceinline__ float bf2f(unsigned short u) {
    return __uint_as_float(((unsigned int)u) << 16);
}
__device__ __forceinline__ bf16x8 pack8(float4 a, float4 b) {
    bf16x8 r;
    r[0] = (short)f2bf(a.x); r[1] = (short)f2bf(a.y);
    r[2] = (short)f2bf(a.z); r[3] = (short)f2bf(a.w);
    r[4] = (short)f2bf(b.x); r[5] = (short)f2bf(b.y);
    r[6] = (short)f2bf(b.z); r[7] = (short)f2bf(b.w);
    return r;
}

// ---- GEMM phase (layers 1,2): A (16 rows bf16) from LDS, B from bf16 Wp (L2-hot).
// 16 waves: nhalf=wv>>3 (0: u-half -> UWu[l&1] bf16; 1: w-half -> UWw fp32+bias),
// sub=wv&7 -> cols sub*32..+31. Epilogue: C/D col=lane&15, row=(lane>>4)*4+reg.
__device__ __forceinline__ void gemm_phase(int l, const short* Alds,
                                           const short* __restrict__ Wp,
                                           const float* __restrict__ bias,
                                           unsigned short* __restrict__ UWu,
                                           float* __restrict__ UWw,
                                           int b, int t) {
    const int wv = t >> 6, lane = t & 63;
    const int lm = lane & 15, kq = lane >> 4;
    const int nhalf = wv >> 3, sub = wv & 7;
    f32x4 acc0 = (f32x4){0.f, 0.f, 0.f, 0.f};
    f32x4 acc1 = (f32x4){0.f, 0.f, 0.f, 0.f};
    const short* ap = Alds + lm * 264 + kq * 8;
    const short* bp = Wp + (size_t)l * 131072
                         + (size_t)(nhalf * 256 + sub * 32 + lm) * 256 + kq * 8;
#pragma unroll
    for (int ks = 0; ks < 8; ++ks) {
        const int ko = ks * 32;
        bf16x8 a  = *(const bf16x8*)(ap + ko);
        bf16x8 q0 = *(const bf16x8*)(bp + ko);
        bf16x8 q1 = *(const bf16x8*)(bp + 16 * 256 + ko);
        acc0 = __builtin_amdgcn_mfma_f32_16x16x32_bf16(a, q0, acc0, 0, 0, 0);
        acc1 = __builtin_amdgcn_mfma_f32_16x16x32_bf16(a, q1, acc1, 0, 0, 0);
    }
    unsigned short* UW = UWu + (size_t)(l & 1) * NODES * 256;
#pragma unroll
    for (int nt2 = 0; nt2 < 2; ++nt2) {
        int nc = sub * 32 + nt2 * 16 + lm;     // col 0..255
        f32x4 av = nt2 ? acc1 : acc0;
        if (nhalf == 0) {
#pragma unroll
            for (int p = 0; p < 4; ++p)
                UW[(size_t)(b * 16 + kq * 4 + p) * 256 + nc] = f2bf(av[p]);
        } else {
            float bc = bias[nc];
#pragma unroll
            for (int p = 0; p < 4; ++p)
                UWw[(size_t)(b * 16 + kq * 4 + p) * 256 + nc] = av[p] + bc;
        }
    }
}

// ---- GEMM from register-resident B fragments (layer 0) ----
__device__ __forceinline__ void gemm_regs(int par, const bf16x8 fb[2][8],
                                          const short* Alds,
                                          const float* __restrict__ bias,
                                          unsigned short* __restrict__ UWu,
                                          float* __restrict__ UWw,
                                          int b, int t) {
    const int wv = t >> 6, lane = t & 63;
    const int lm = lane & 15, kq = lane >> 4;
    const int nhalf = wv >> 3, sub = wv & 7;
    f32x4 acc0 = (f32x4){0.f, 0.f, 0.f, 0.f};
    f32x4 acc1 = (f32x4){0.f, 0.f, 0.f, 0.f};
    const short* ap = Alds + lm * 264 + kq * 8;
#pragma unroll
    for (int ks = 0; ks < 8; ++ks) {
        bf16x8 a = *(const bf16x8*)(ap + ks * 32);
        acc0 = __builtin_amdgcn_mfma_f32_16x16x32_bf16(a, fb[0][ks], acc0, 0, 0, 0);
        acc1 = __builtin_amdgcn_mfma_f32_16x16x32_bf16(a, fb[1][ks], acc1, 0, 0, 0);
    }
    unsigned short* UW = UWu + (size_t)par * NODES * 256;
#pragma unroll
    for (int nt2 = 0; nt2 < 2; ++nt2) {
        int nc = sub * 32 + nt2 * 16 + lm;     // col 0..255
        f32x4 av = nt2 ? acc1 : acc0;
        if (nhalf == 0) {
#pragma unroll
            for (int p = 0; p < 4; ++p)
                UW[(size_t)(b * 16 + kq * 4 + p) * 256 + nc] = f2bf(av[p]);
        } else {
            float bc = bias[nc];
#pragma unroll
            for (int p = 0; p < 4; ++p)
                UWw[(size_t)(b * 16 + kq * 4 + p) * 256 + nc] = av[p] + bc;
        }
    }
}

// ---- edge phase: 1 node/wave (16 nodes/block). Gathers u[src] bf16 rows
// (8 B/lane, coalesced 512 B/row), max-reduce, + w[dst] (own UWw row), relu,
// write out and (if AldsW) the next layer's A row into LDS.
__device__ __forceinline__ void edge_phase(int l,
                                           const unsigned short* __restrict__ UWu,
                                           const float* __restrict__ UWw,
                                           const int* __restrict__ degG,
                                           const int* __restrict__ srcS,
                                           float* __restrict__ out,
                                           short* AldsW, int b, int t) {
    const int wv = t >> 6, lane = t & 63;
    const int i = b * 16 + wv;
    int deg = degG[i]; if (deg > DEGCAP) deg = DEGCAP;
    const int beg = i * DEGCAP, end = beg + deg;
    const unsigned short* UW = UWu + (size_t)(l & 1) * NODES * 256;
    const float NEG = -3.4e38f;
    float mx0 = NEG, mx1 = NEG, mx2 = NEG, mx3 = NEG;
    int e = beg;
    for (; e + 8 <= end; e += 8) {
        int4 sa = *(const int4*)(srcS + e);      // bucket base 256B-aligned,
        int4 sb = *(const int4*)(srcS + e + 4);  // e steps 32B -> int4-safe
        ushort4 v0 = *(const ushort4*)(UW + (size_t)sa.x * 256 + lane * 4);
        ushort4 v1 = *(const ushort4*)(UW + (size_t)sa.y * 256 + lane * 4);
        ushort4 v2 = *(const ushort4*)(UW + (size_t)sa.z * 256 + lane * 4);
        ushort4 v3 = *(const ushort4*)(UW + (size_t)sa.w * 256 + lane * 4);
        ushort4 v4 = *(const ushort4*)(UW + (size_t)sb.x * 256 + lane * 4);
        ushort4 v5 = *(const ushort4*)(UW + (size_t)sb.y * 256 + lane * 4);
        ushort4 v6 = *(const ushort4*)(UW + (size_t)sb.z * 256 + lane * 4);
        ushort4 v7 = *(const ushort4*)(UW + (size_t)sb.w * 256 + lane * 4);
        mx0 = fmaxf(mx0, fmaxf(fmaxf(bf2f(v0.x), bf2f(v1.x)), fmaxf(bf2f(v2.x), bf2f(v3.x))));
        mx0 = fmaxf(mx0, fmaxf(fmaxf(bf2f(v4.x), bf2f(v5.x)), fmaxf(bf2f(v6.x), bf2f(v7.x))));
        mx1 = fmaxf(mx1, fmaxf(fmaxf(bf2f(v0.y), bf2f(v1.y)), fmaxf(bf2f(v2.y), bf2f(v3.y))));
        mx1 = fmaxf(mx1, fmaxf(fmaxf(bf2f(v4.y), bf2f(v5.y)), fmaxf(bf2f(v6.y), bf2f(v7.y))));
        mx2 = fmaxf(mx2, fmaxf(fmaxf(bf2f(v0.z), bf2f(v1.z)), fmaxf(bf2f(v2.z), bf2f(v3.z))));
        mx2 = fmaxf(mx2, fmaxf(fmaxf(bf2f(v4.z), bf2f(v5.z)), fmaxf(bf2f(v6.z), bf2f(v7.z))));
        mx3 = fmaxf(mx3, fmaxf(fmaxf(bf2f(v0.w), bf2f(v1.w)), fmaxf(bf2f(v2.w), bf2f(v3.w))));
        mx3 = fmaxf(mx3, fmaxf(fmaxf(bf2f(v4.w), bf2f(v5.w)), fmaxf(bf2f(v6.w), bf2f(v7.w))));
    }
    for (; e + 4 <= end; e += 4) {
        int4 sa = *(const int4*)(srcS + e);
        ushort4 v0 = *(const ushort4*)(UW + (size_t)sa.x * 256 + lane * 4);
        ushort4 v1 = *(const ushort4*)(UW + (size_t)sa.y * 256 + lane * 4);
        ushort4 v2 = *(const ushort4*)(UW + (size_t)sa.z * 256 + lane * 4);
        ushort4 v3 = *(const ushort4*)(UW + (size_t)sa.w * 256 + lane * 4);
        mx0 = fmaxf(mx0, fmaxf(fmaxf(bf2f(v0.x), bf2f(v1.x)), fmaxf(bf2f(v2.x), bf2f(v3.x))));
        mx1 = fmaxf(mx1, fmaxf(fmaxf(bf2f(v0.y), bf2f(v1.y)), fmaxf(bf2f(v2.y), bf2f(v3.y))));
        mx2 = fmaxf(mx2, fmaxf(fmaxf(bf2f(v0.z), bf2f(v1.z)), fmaxf(bf2f(v2.z), bf2f(v3.z))));
        mx3 = fmaxf(mx3, fmaxf(fmaxf(bf2f(v0.w), bf2f(v1.w)), fmaxf(bf2f(v2.w), bf2f(v3.w))));
    }
    for (; e < end; ++e) {
        int s = srcS[e];
        ushort4 v = *(const ushort4*)(UW + (size_t)s * 256 + lane * 4);
        mx0 = fmaxf(mx0, bf2f(v.x)); mx1 = fmaxf(mx1, bf2f(v.y));
        mx2 = fmaxf(mx2, bf2f(v.z)); mx3 = fmaxf(mx3, bf2f(v.w));
    }
    float4 w4 = *(const float4*)(UWw + (size_t)i * 256 + lane * 4);
    f32x4 r;
    // empty segment: mx=-3.4e38 -> mx+w<0 -> relu 0 (PyG fill semantics)
    r[0] = fmaxf(mx0 + w4.x, 0.0f);
    r[1] = fmaxf(mx1 + w4.y, 0.0f);
    r[2] = fmaxf(mx2 + w4.z, 0.0f);
    r[3] = fmaxf(mx3 + w4.w, 0.0f);
    *(f32x4*)(out + (size_t)i * OSTR + (l + 1) * 256 + lane * 4) = r;
    if (AldsW) {
        ushort4 rb;
        rb.x = f2bf(r[0]); rb.y = f2bf(r[1]); rb.z = f2bf(r[2]); rb.w = f2bf(r[3]);
        *(ushort4*)(AldsW + wv * 264 + lane * 4) = rb;   // next layer's A row
    }
}

// ---------- k_g0: x0 copy + Wp(1,2) prep + dst-scan scatter + gemm0 ----------
__global__ __launch_bounds__(1024, 4) void k_g0(const float* __restrict__ x0,
                                                const int* __restrict__ srcIdx,
                                                const int* __restrict__ dstIdx,
                                                const float* __restrict__ W0,
                                                const float* __restrict__ W1,
                                                const float* __restrict__ W2,
                                                const float* __restrict__ B0,
                                                short* __restrict__ Wp,
                                                unsigned short* __restrict__ UWu,
                                                float* __restrict__ UWw,
                                                int* __restrict__ degG,
                                                int* __restrict__ srcS,
                                                float* __restrict__ out) {
    __shared__ __align__(16) short Alds[16 * 264];
    __shared__ int degL[16];
    const int t = threadIdx.x, b = blockIdx.x;
    const int gtid = b * 1024 + t;                   // 0..262143
    if (t < 16) degL[t] = 0;
    {
        // block b owns nodes b*16..+15: single x0 read feeds out copy AND A-tile
        int row = t >> 6, c4 = t & 63;               // 16 rows x 64 f32x4
        f32x4 v = *((const f32x4*)x0 + (size_t)(b * 16 + row) * 64 + c4);
        ((f32x4*)out)[(size_t)(b * 16 + row) * 256 + c4] = v;
        ushort4 hb;
        hb.x = f2bf(v[0]); hb.y = f2bf(v[1]); hb.z = f2bf(v[2]); hb.w = f2bf(v[3]);
        *(ushort4*)(Alds + row * 264 + c4 * 4) = hb;
    }
    {
        // Wp prep layers 1,2: gtid spans exactly 2 x 131072 -> Wp[131072+gtid]
        const float* W = (gtid >= 131072) ? W2 : W1;
        int idx = gtid & 131071;
        int n2 = idx >> 8, c = idx & 255;
        float wv2 = (n2 < 256) ? W[n2 * 512 + c]                                    // Wa
                               : W[(n2 - 256) * 512 + 256 + c] - W[(n2 - 256) * 512 + c]; // Wb-Wa
        Wp[131072 + gtid] = (short)f2bf(wv2);
    }
    // gemm0 B fragments W0-direct (fp32 -> bf16 in regs; live only in this kernel)
    const int wv = t >> 6, lane = t & 63;
    const int lm = lane & 15, kq = lane >> 4;
    const int nhalf = wv >> 3, sub = wv & 7;
    bf16x8 fb[2][8];
    {
        const int r0 = sub * 32 + lm;
#pragma unroll
        for (int rr = 0; rr < 2; ++rr) {
            const float* rp = W0 + (size_t)(r0 + rr * 16) * 512 + kq * 8;
#pragma unroll
            for (int ks = 0; ks < 8; ++ks) {
                const int ko = ks * 32;
                if (nhalf == 0) {
                    fb[rr][ks] = pack8(*(const float4*)(rp + ko),
                                       *(const float4*)(rp + ko + 4));
                } else {
                    float4 a0 = *(const float4*)(rp + ko);
                    float4 a1 = *(const float4*)(rp + ko + 4);
                    float4 c0 = *(const float4*)(rp + 256 + ko);
                    float4 c1 = *(const float4*)(rp + 256 + ko + 4);
                    float4 d0, d1;
                    d0.x = c0.x - a0.x; d0.y = c0.y - a0.y;
                    d0.z = c0.z - a0.z; d0.w = c0.w - a0.w;
                    d1.x = c1.x - a1.x; d1.y = c1.y - a1.y;
                    d1.z = c1.z - a1.z; d1.w = c1.w - a1.w;
                    fb[rr][ks] = pack8(d0, d1);
                }
            }
        }
    }
    __syncthreads();   // degL zeroed, Alds staged
    // cursor-free scatter: scan all dst (int4 coalesced, 256KB L2-resident);
    // claim edges for this block's 16 nodes via LDS atomics.
#pragma unroll 4
    for (int j = 0; j < 16; ++j) {
        int4 dv = ((const int4*)dstIdx)[j * 1024 + t];
        int e0 = (j * 1024 + t) * 4;
#pragma unroll
        for (int k = 0; k < 4; ++k) {
            int d = (&dv.x)[k];
            if ((d >> 4) == b) {
                int p = atomicAdd(&degL[d & 15], 1);
                if (p < DEGCAP) srcS[d * DEGCAP + p] = srcIdx[e0 + k];
            }
        }
    }
    __syncthreads();   // degL final
    if (t < 16) degG[b * 16 + t] = degL[t];
    gemm_regs(0, fb, Alds, B0, UWu, UWw, b, t);
}

// ---------- k_eg: edge layer l, then gemm layer l+1 (LDS handoff) ----------
__global__ __launch_bounds__(1024, 4) void k_eg(int l,
                                                const short* __restrict__ Wp,
                                                const float* __restrict__ biasN,
                                                unsigned short* __restrict__ UWu,
                                                float* __restrict__ UWw,
                                                const int* __restrict__ degG,
                                                const int* __restrict__ srcS,
                                                float* __restrict__ out) {
    __shared__ __align__(16) short Alds[16 * 264];
    const int t = threadIdx.x, b = blockIdx.x;
    edge_phase(l, UWu, UWw, degG, srcS, out, Alds, b, t);
    __syncthreads();   // Alds rows complete; UWw rows (own) consumed
    gemm_phase(l + 1, Alds, Wp, biasN, UWu, UWw, b, t);
}

// ---------- k_e2: final edge layer ----------
__global__ __launch_bounds__(1024, 4) void k_e2(const unsigned short* __restrict__ UWu,
                                                const float* __restrict__ UWw,
                                                const int* __restrict__ degG,
                                                const int* __restrict__ srcS,
                                                float* __restrict__ out) {
    const int t = threadIdx.x, b = blockIdx.x;
    edge_phase(2, UWu, UWw, degG, srcS, out, (short*)nullptr, b, t);
}

extern "C" void kernel_launch(void* const* d_in, const int* in_sizes, int n_in,
                              void* d_out, int out_size, void* d_ws, size_t ws_size,
                              hipStream_t stream) {
    const float* x0 = (const float*)d_in[0];
    const int* ei = (const int*)d_in[1];
    const int* srcIdx = ei;          // edge_index[0]
    const int* dstIdx = ei + EDGES;  // edge_index[1]
    float* out = (float*)d_out;

    // ws layout (~9.8 MB):
    char* w = (char*)d_ws;
    unsigned short* UWu = (unsigned short*)w;          // 4 MB: 2 x [4096][256] bf16
    float* UWw = (float*)(w + 4194304);                // 4 MB: [4096][256] fp32
    short* Wp = (short*)(w + 8388608);                 // 768 KB: 3 x [512][256] bf16 (layer0 unused)
    int* srcS = (int*)(w + 9175040);                   // 1 MB: [4096][64]
    int* degG = (int*)(w + 10223616);                  // 16 KB (written by k_g0)

    const float* W0 = (const float*)d_in[2]; const float* B0 = (const float*)d_in[3];
    const float* W1 = (const float*)d_in[4]; const float* B1 = (const float*)d_in[5];
    const float* W2 = (const float*)d_in[6]; const float* B2 = (const float*)d_in[7];

    k_g0<<<256, 1024, 0, stream>>>(x0, srcIdx, dstIdx, W0, W1, W2, B0,
                                   Wp, UWu, UWw, degG, srcS, out);
    k_eg<<<256, 1024, 0, stream>>>(0, Wp, B1, UWu, UWw, degG, srcS, out);
    k_eg<<<256, 1024, 0, stream>>>(1, Wp, B2, UWu, UWw, degG, srcS, out);
    k_e2<<<256, 1024, 0, stream>>>(UWu, UWw, degG, srcS, out);
}

// Round 12
// 130.804 us; speedup vs baseline: 1.1443x; 1.1443x over previous
//
#include <hip/hip_runtime.h>

// GNN EdgeConv, 3 layers, fp32 in/out.
// msg_e = relu(u[src]+w[dst]);  u = x@Wa^T (bf16), w = x@(Wb-Wa)^T + b (fp32).
// Round-15: REVERT to round-13 (measured best: 131.26us, 5 dispatches).
// Round-14's cursor-free per-block dst-scan cost 64MB of aggregate L2 reads
// (256 blocks x full 256KB edge list) serialized inside k_g0 -> +18us.
// Ledger of structural experiments: r11 (merge prep+gemm0, W0-direct+held-regs)
// -18us; r13 (re-partition, delete memset) +1us; r14 (delete k_prep, dst-scan)
// -18us. The 5-dispatch pipeline below is the plateau of this search:
//   k_prep: Wp bf16 pack (3 layers) + cursor zero
//   k_g0:   x0->out copy (own rows) + bucket scatter + gemm0 (B from L2-hot Wp)
//   k_eg(0), k_eg(1): edge_l (gather-max over dst-sorted buckets) + gemm_{l+1}
//                     with LDS handoff of the block's own 16 rows
//   k_e2:   final edge layer
// No pipe >15% on our kernels; remaining time = harness re-poison fills +
// launch boundaries. Practical plateau.

#define NODES 4096
#define EDGES 65536
#define OSTR 1024   // out row stride (fp32)
#define DEGCAP 64   // max bucket size; deg ~ Poisson(16), P(>64) ~ 1e-18

typedef __attribute__((ext_vector_type(8))) short bf16x8;
typedef __attribute__((ext_vector_type(4))) float f32x4;

__device__ __forceinline__ unsigned short f2bf(float f) {
    unsigned int x = __float_as_uint(f);
    return (unsigned short)((x + 0x7fff + ((x >> 16) & 1)) >> 16); // RNE
}
__device__ __forceinline__ float bf2f(unsigned short u) {
    return __uint_as_float(((unsigned int)u) << 16);
}

// ---- GEMM phase: A (16 rows bf16) from LDS, B from packed Wp bf16 (L2-hot).
// 16 waves: nhalf=wv>>3 (0: u-half -> UWu[l&1] bf16; 1: w-half -> UWw fp32+bias),
// sub=wv&7 -> cols sub*32..+31. Epilogue: C/D col=lane&15, row=(lane>>4)*4+reg.
__device__ __forceinline__ void gemm_phase(int l, const short* Alds,
                                           const short* __restrict__ Wp,
                                           const float* __restrict__ bias,
                                           unsigned short* __restrict__ UWu,
                                           float* __restrict__ UWw,
                                           int b, int t) {
    const int wv = t >> 6, lane = t & 63;
    const int lm = lane & 15, kq = lane >> 4;
    const int nhalf = wv >> 3, sub = wv & 7;
    f32x4 acc0 = (f32x4){0.f, 0.f, 0.f, 0.f};
    f32x4 acc1 = (f32x4){0.f, 0.f, 0.f, 0.f};
    const short* ap = Alds + lm * 264 + kq * 8;
    const short* bp = Wp + (size_t)l * 131072
                         + (size_t)(nhalf * 256 + sub * 32 + lm) * 256 + kq * 8;
#pragma unroll
    for (int ks = 0; ks < 8; ++ks) {
        const int ko = ks * 32;
        bf16x8 a  = *(const bf16x8*)(ap + ko);
        bf16x8 q0 = *(const bf16x8*)(bp + ko);
        bf16x8 q1 = *(const bf16x8*)(bp + 16 * 256 + ko);
        acc0 = __builtin_amdgcn_mfma_f32_16x16x32_bf16(a, q0, acc0, 0, 0, 0);
        acc1 = __builtin_amdgcn_mfma_f32_16x16x32_bf16(a, q1, acc1, 0, 0, 0);
    }
    unsigned short* UW = UWu + (size_t)(l & 1) * NODES * 256;
#pragma unroll
    for (int nt2 = 0; nt2 < 2; ++nt2) {
        int nc = sub * 32 + nt2 * 16 + lm;     // col 0..255
        f32x4 av = nt2 ? acc1 : acc0;
        if (nhalf == 0) {
#pragma unroll
            for (int p = 0; p < 4; ++p)
                UW[(size_t)(b * 16 + kq * 4 + p) * 256 + nc] = f2bf(av[p]);
        } else {
            float bc = bias[nc];
#pragma unroll
            for (int p = 0; p < 4; ++p)
                UWw[(size_t)(b * 16 + kq * 4 + p) * 256 + nc] = av[p] + bc;
        }
    }
}

// ---- edge phase: 1 node/wave (16 nodes/block). Gathers u[src] bf16 rows
// (8 B/lane, coalesced 512 B/row), max-reduce, + w[dst] (own UWw row), relu,
// write out and (if AldsW) the next layer's A row into LDS.
__device__ __forceinline__ void edge_phase(int l,
                                           const unsigned short* __restrict__ UWu,
                                           const float* __restrict__ UWw,
                                           const int* __restrict__ cursor,
                                           const int* __restrict__ srcS,
                                           float* __restrict__ out,
                                           short* AldsW, int b, int t) {
    const int wv = t >> 6, lane = t & 63;
    const int i = b * 16 + wv;
    int deg = cursor[i]; if (deg > DEGCAP) deg = DEGCAP;
    const int beg = i * DEGCAP, end = beg + deg;
    const unsigned short* UW = UWu + (size_t)(l & 1) * NODES * 256;
    const float NEG = -3.4e38f;
    float mx0 = NEG, mx1 = NEG, mx2 = NEG, mx3 = NEG;
    int e = beg;
    for (; e + 8 <= end; e += 8) {
        int4 sa = *(const int4*)(srcS + e);      // bucket base 256B-aligned,
        int4 sb = *(const int4*)(srcS + e + 4);  // e steps 32B -> int4-safe
        ushort4 v0 = *(const ushort4*)(UW + (size_t)sa.x * 256 + lane * 4);
        ushort4 v1 = *(const ushort4*)(UW + (size_t)sa.y * 256 + lane * 4);
        ushort4 v2 = *(const ushort4*)(UW + (size_t)sa.z * 256 + lane * 4);
        ushort4 v3 = *(const ushort4*)(UW + (size_t)sa.w * 256 + lane * 4);
        ushort4 v4 = *(const ushort4*)(UW + (size_t)sb.x * 256 + lane * 4);
        ushort4 v5 = *(const ushort4*)(UW + (size_t)sb.y * 256 + lane * 4);
        ushort4 v6 = *(const ushort4*)(UW + (size_t)sb.z * 256 + lane * 4);
        ushort4 v7 = *(const ushort4*)(UW + (size_t)sb.w * 256 + lane * 4);
        mx0 = fmaxf(mx0, fmaxf(fmaxf(bf2f(v0.x), bf2f(v1.x)), fmaxf(bf2f(v2.x), bf2f(v3.x))));
        mx0 = fmaxf(mx0, fmaxf(fmaxf(bf2f(v4.x), bf2f(v5.x)), fmaxf(bf2f(v6.x), bf2f(v7.x))));
        mx1 = fmaxf(mx1, fmaxf(fmaxf(bf2f(v0.y), bf2f(v1.y)), fmaxf(bf2f(v2.y), bf2f(v3.y))));
        mx1 = fmaxf(mx1, fmaxf(fmaxf(bf2f(v4.y), bf2f(v5.y)), fmaxf(bf2f(v6.y), bf2f(v7.y))));
        mx2 = fmaxf(mx2, fmaxf(fmaxf(bf2f(v0.z), bf2f(v1.z)), fmaxf(bf2f(v2.z), bf2f(v3.z))));
        mx2 = fmaxf(mx2, fmaxf(fmaxf(bf2f(v4.z), bf2f(v5.z)), fmaxf(bf2f(v6.z), bf2f(v7.z))));
        mx3 = fmaxf(mx3, fmaxf(fmaxf(bf2f(v0.w), bf2f(v1.w)), fmaxf(bf2f(v2.w), bf2f(v3.w))));
        mx3 = fmaxf(mx3, fmaxf(fmaxf(bf2f(v4.w), bf2f(v5.w)), fmaxf(bf2f(v6.w), bf2f(v7.w))));
    }
    for (; e + 4 <= end; e += 4) {
        int4 sa = *(const int4*)(srcS + e);
        ushort4 v0 = *(const ushort4*)(UW + (size_t)sa.x * 256 + lane * 4);
        ushort4 v1 = *(const ushort4*)(UW + (size_t)sa.y * 256 + lane * 4);
        ushort4 v2 = *(const ushort4*)(UW + (size_t)sa.z * 256 + lane * 4);
        ushort4 v3 = *(const ushort4*)(UW + (size_t)sa.w * 256 + lane * 4);
        mx0 = fmaxf(mx0, fmaxf(fmaxf(bf2f(v0.x), bf2f(v1.x)), fmaxf(bf2f(v2.x), bf2f(v3.x))));
        mx1 = fmaxf(mx1, fmaxf(fmaxf(bf2f(v0.y), bf2f(v1.y)), fmaxf(bf2f(v2.y), bf2f(v3.y))));
        mx2 = fmaxf(mx2, fmaxf(fmaxf(bf2f(v0.z), bf2f(v1.z)), fmaxf(bf2f(v2.z), bf2f(v3.z))));
        mx3 = fmaxf(mx3, fmaxf(fmaxf(bf2f(v0.w), bf2f(v1.w)), fmaxf(bf2f(v2.w), bf2f(v3.w))));
    }
    for (; e < end; ++e) {
        int s = srcS[e];
        ushort4 v = *(const ushort4*)(UW + (size_t)s * 256 + lane * 4);
        mx0 = fmaxf(mx0, bf2f(v.x)); mx1 = fmaxf(mx1, bf2f(v.y));
        mx2 = fmaxf(mx2, bf2f(v.z)); mx3 = fmaxf(mx3, bf2f(v.w));
    }
    float4 w4 = *(const float4*)(UWw + (size_t)i * 256 + lane * 4);
    f32x4 r;
    // empty segment: mx=-3.4e38 -> mx+w<0 -> relu 0 (PyG fill semantics)
    r[0] = fmaxf(mx0 + w4.x, 0.0f);
    r[1] = fmaxf(mx1 + w4.y, 0.0f);
    r[2] = fmaxf(mx2 + w4.z, 0.0f);
    r[3] = fmaxf(mx3 + w4.w, 0.0f);
    *(f32x4*)(out + (size_t)i * OSTR + (l + 1) * 256 + lane * 4) = r;
    if (AldsW) {
        ushort4 rb;
        rb.x = f2bf(r[0]); rb.y = f2bf(r[1]); rb.z = f2bf(r[2]); rb.w = f2bf(r[3]);
        *(ushort4*)(AldsW + wv * 264 + lane * 4) = rb;   // next layer's A row
    }
}

// ---------- k_prep: Wp (3 layers) + cursor zero. 512 x 256 threads. ----------
__global__ __launch_bounds__(256) void k_prep(const float* __restrict__ W0,
                                              const float* __restrict__ W1,
                                              const float* __restrict__ W2,
                                              short* __restrict__ Wp,
                                              int* __restrict__ cursor) {
    int tid = blockIdx.x * 256 + threadIdx.x;        // 0..131071
    const float* Ws[3] = {W0, W1, W2};
#pragma unroll
    for (int layer = 0; layer < 3; ++layer) {        // one elem per layer per thread
        const float* W = Ws[layer];
        int n2 = tid >> 8, c = tid & 255;
        float wv2 = (n2 < 256) ? W[n2 * 512 + c]                                    // Wa
                               : W[(n2 - 256) * 512 + 256 + c] - W[(n2 - 256) * 512 + c]; // Wb-Wa
        Wp[layer * 131072 + tid] = (short)f2bf(wv2);
    }
    if (tid < NODES) cursor[tid] = 0;
}

// ---------- k_g0: x0->out copy (own rows) + bucket scatter + gemm layer 0 ----
__global__ __launch_bounds__(1024, 4) void k_g0(const float* __restrict__ x0,
                                                const int* __restrict__ srcIdx,
                                                const int* __restrict__ dstIdx,
                                                const short* __restrict__ Wp,
                                                const float* __restrict__ B0,
                                                unsigned short* __restrict__ UWu,
                                                float* __restrict__ UWw,
                                                int* __restrict__ cursor,
                                                int* __restrict__ srcS,
                                                float* __restrict__ out) {
    __shared__ __align__(16) short Alds[16 * 264];
    const int t = threadIdx.x, b = blockIdx.x;
    const int gtid = b * 1024 + t;                   // 0..262143
    {
        // block b owns nodes b*16..+15: single x0 read feeds out copy AND A-tile
        int row = t >> 6, c4 = t & 63;               // 16 rows x 64 f32x4
        f32x4 v = *((const f32x4*)x0 + (size_t)(b * 16 + row) * 64 + c4);
        ((f32x4*)out)[(size_t)(b * 16 + row) * 256 + c4] = v;
        ushort4 hb;
        hb.x = f2bf(v[0]); hb.y = f2bf(v[1]); hb.z = f2bf(v[2]); hb.w = f2bf(v[3]);
        *(ushort4*)(Alds + row * 264 + c4 * 4) = hb;
    }
    // bucket scatter (cursor zeroed by k_prep, dispatch-ordered; consumer is
    // max so in-bucket order is irrelevant). Overlaps gemm0's MFMA phase.
    if (gtid < EDGES) {
        int d = dstIdx[gtid];
        int p = atomicAdd(&cursor[d], 1);
        if (p < DEGCAP) srcS[d * DEGCAP + p] = srcIdx[gtid];
    }
    __syncthreads();
    gemm_phase(0, Alds, Wp, B0, UWu, UWw, b, t);
}

// ---------- k_eg: edge layer l, then gemm layer l+1 (LDS handoff) ----------
__global__ __launch_bounds__(1024, 4) void k_eg(int l,
                                                const short* __restrict__ Wp,
                                                const float* __restrict__ biasN,
                                                unsigned short* __restrict__ UWu,
                                                float* __restrict__ UWw,
                                                const int* __restrict__ cursor,
                                                const int* __restrict__ srcS,
                                                float* __restrict__ out) {
    __shared__ __align__(16) short Alds[16 * 264];
    const int t = threadIdx.x, b = blockIdx.x;
    edge_phase(l, UWu, UWw, cursor, srcS, out, Alds, b, t);
    __syncthreads();   // Alds rows complete; UWw rows (own) consumed
    gemm_phase(l + 1, Alds, Wp, biasN, UWu, UWw, b, t);
}

// ---------- k_e2: final edge layer ----------
__global__ __launch_bounds__(1024, 4) void k_e2(const unsigned short* __restrict__ UWu,
                                                const float* __restrict__ UWw,
                                                const int* __restrict__ cursor,
                                                const int* __restrict__ srcS,
                                                float* __restrict__ out) {
    const int t = threadIdx.x, b = blockIdx.x;
    edge_phase(2, UWu, UWw, cursor, srcS, out, (short*)nullptr, b, t);
}

extern "C" void kernel_launch(void* const* d_in, const int* in_sizes, int n_in,
                              void* d_out, int out_size, void* d_ws, size_t ws_size,
                              hipStream_t stream) {
    const float* x0 = (const float*)d_in[0];
    const int* ei = (const int*)d_in[1];
    const int* srcIdx = ei;          // edge_index[0]
    const int* dstIdx = ei + EDGES;  // edge_index[1]
    float* out = (float*)d_out;

    // ws layout (~9.8 MB):
    char* w = (char*)d_ws;
    unsigned short* UWu = (unsigned short*)w;          // 4 MB: 2 x [4096][256] bf16
    float* UWw = (float*)(w + 4194304);                // 4 MB: [4096][256] fp32
    short* Wp = (short*)(w + 8388608);                 // 768 KB: 3 x [512][256] bf16
    int* srcS = (int*)(w + 9175040);                   // 1 MB: [4096][64]
    int* cursor = (int*)(w + 10223616);                // 16 KB (zeroed by k_prep)

    const float* W0 = (const float*)d_in[2]; const float* B0 = (const float*)d_in[3];
    const float* W1 = (const float*)d_in[4]; const float* B1 = (const float*)d_in[5];
    const float* W2 = (const float*)d_in[6]; const float* B2 = (const float*)d_in[7];

    k_prep<<<512, 256, 0, stream>>>(W0, W1, W2, Wp, cursor);
    k_g0<<<256, 1024, 0, stream>>>(x0, srcIdx, dstIdx, Wp, B0, UWu, UWw, cursor, srcS, out);
    k_eg<<<256, 1024, 0, stream>>>(0, Wp, B1, UWu, UWw, cursor, srcS, out);
    k_eg<<<256, 1024, 0, stream>>>(1, Wp, B2, UWu, UWw, cursor, srcS, out);
    k_e2<<<256, 1024, 0, stream>>>(UWu, UWw, cursor, srcS, out);
}